// Round 4
// baseline (1715.833 us; speedup 1.0000x reference)
//
#include <hip/hip_runtime.h>

// Residual VQ, bit-exact replication of the numpy reference's fp32 rounding.
// B=16 S=2048 D=64 K=8 M=2048.
//
// Numerics contract (verified bit-exact R1-R3, absmax 0.0):
//  - r2/c2: numpy pairwise_sum 8-accumulator order, no FMA contraction
//  - cross: numpy einsum baseline-SSE order: 4 chains (d mod 4), per 16-block
//           groups at offsets {12,8,4,0}+j, blocks ascending, hsum (L0+L1)+(L2+L3)
//  - t = fl(r2 - 2*cross) via fmaf(-2,cross,r2); d2 = fl(t + c2)
//  - argmin: first occurrence (strict <; cross-chunk combine ascending-m)
//
// R4: inner loop emitted as explicit v_pk_mul_f32/v_pk_add_f32 inline asm
// (per-half IEEE-RN == scalar, so bit-exactness preserved). Codebook pairs
// bound with "s" constraints (stay in SGPRs from s_load, feed VOP3P's scalar
// slot — no v_mov). rp[] used as asm "v" operands at every use -> must stay
// arch-VGPR-resident (R3's VGPR=52 proved the allocator was AGPR-shuffling).

#define BB 16
#define SS 2048
#define DD 64
#define KK 8
#define MM 2048
#define NPTS (BB * SS)      // 32768
#define QSIZE (NPTS * DD)   // 2097152
#define WPB 8               // waves per block
#define MCHUNK (MM / WPB)   // 256 m per wave

typedef float v2f __attribute__((ext_vector_type(2)));

// ---- prep: c2[k][m] (numpy pairwise) ----
__global__ __launch_bounds__(256) void rvq_prep(const float* __restrict__ cb,
                                                float* __restrict__ c2) {
#pragma clang fp contract(off)
    int tid = blockIdx.x * 256 + threadIdx.x;  // 0 .. K*M-1
    const float* row = cb + (size_t)tid * DD;
    float r[8];
#pragma unroll
    for (int j = 0; j < 8; ++j) { float v = row[j]; r[j] = v * v; }
#pragma unroll
    for (int i = 8; i < DD; i += 8) {
#pragma unroll
        for (int j = 0; j < 8; ++j) { float v = row[i + j]; float t = v * v; r[j] += t; }
    }
    c2[tid] = ((r[0] + r[1]) + (r[2] + r[3])) + ((r[4] + r[5]) + (r[6] + r[7]));
}

// ---- one RVQ step ----
// grid = NPTS/64 = 512 blocks x 512 threads (8 waves).
// lane = point within the block's 64-point group; wave = m-chunk.
__global__ __launch_bounds__(512, 3) void rvq_step(const float* __restrict__ res_in,
                                                   float* __restrict__ res_out,
                                                   const float* __restrict__ cbk,  // (M,D)
                                                   const float* __restrict__ c2k,  // (M,)
                                                   float* __restrict__ idx_out) {  // (NPTS,)
#pragma clang fp contract(off)
    const int tid = threadIdx.x;
    const int lane = tid & 63;
    const int wv = __builtin_amdgcn_readfirstlane(tid >> 6);  // wave-uniform
    const int point = blockIdx.x * 64 + lane;

    // --- load this lane's residual (64 floats) into 32 v2f regs, once ---
    v2f rp[DD / 2];
    {
        const float4* rr4 = (const float4*)(res_in + (size_t)point * DD);
#pragma unroll
        for (int i = 0; i < DD / 4; ++i) {
            float4 v = rr4[i];
            rp[2 * i + 0] = (v2f){v.x, v.y};
            rp[2 * i + 1] = (v2f){v.z, v.w};
        }
    }

    // --- r2, numpy pairwise 8-accumulator order (pairs {j,j+1} packed) ---
    v2f A[4];
#pragma unroll
    for (int j = 0; j < 4; ++j) A[j] = rp[j] * rp[j];
#pragma unroll
    for (int i = 8; i < DD; i += 8) {
#pragma unroll
        for (int j = 0; j < 4; ++j) { v2f t = rp[i / 2 + j] * rp[i / 2 + j]; A[j] += t; }
    }
    const float r2 = ((A[0].x + A[0].y) + (A[1].x + A[1].y))
                   + ((A[2].x + A[2].y) + (A[3].x + A[3].y));

    // --- scan this wave's m-chunk, lane-local argmin ---
    float best = __builtin_inff();
    int bidx = 0;
    const int m0 = wv * MCHUNK;
#pragma unroll 2
    for (int mi = 0; mi < MCHUNK; ++mi) {
        const int m = m0 + mi;
        const v2f* crow2 = (const v2f*)(cbk + (size_t)m * DD);  // wave-uniform -> s_load
        const float c2m = c2k[m];
        v2f ch01 = {0.0f, 0.0f};   // chains j=0,1
        v2f ch23 = {0.0f, 0.0f};   // chains j=2,3
        // einsum chain order: 16-blocks ascending; within, groups at offsets 12,8,4,0
#pragma unroll
        for (int b = 0; b < DD; b += 16) {
#pragma unroll
            for (int g = 3; g >= 0; --g) {
                const int i0 = (b + g * 4) >> 1;
                const v2f c01 = crow2[i0];       // uniform -> SGPR pair
                const v2f c23 = crow2[i0 + 1];
                v2f t01, t23;
                asm("v_pk_mul_f32 %0, %1, %2" : "=v"(t01) : "s"(c01), "v"(rp[i0]));
                asm("v_pk_mul_f32 %0, %1, %2" : "=v"(t23) : "s"(c23), "v"(rp[i0 + 1]));
                asm("v_pk_add_f32 %0, %0, %1" : "+v"(ch01) : "v"(t01));
                asm("v_pk_add_f32 %0, %0, %1" : "+v"(ch23) : "v"(t23));
            }
        }
        const float cross = (ch01.x + ch01.y) + (ch23.x + ch23.y);
        const float tt = __builtin_fmaf(-2.0f, cross, r2);  // == fl(r2 - 2*cross)
        const float d2 = tt + c2m;
        if (d2 < best) { best = d2; bidx = m; }
    }

    // --- combine across the 8 m-chunks (waves), first-occurrence semantics ---
    __shared__ float sb[WPB * 64];
    __shared__ int   si[WPB * 64];
    __shared__ int   fidx[64];
    sb[wv * 64 + lane] = best;
    si[wv * 64 + lane] = bidx;
    __syncthreads();
    if (tid < 64) {
        float b = sb[lane];
        int ix = si[lane];
#pragma unroll
        for (int w = 1; w < WPB; ++w) {
            float ob = sb[w * 64 + lane];
            int oi = si[w * 64 + lane];
            if (ob < b) { b = ob; ix = oi; }  // strict <: smaller-m chunk wins ties
        }
        fidx[lane] = ix;
        idx_out[point] = (float)ix;  // exact for ix < 2^24
    }
    __syncthreads();

    // --- residual update: 512 threads x 8 elems, coalesced on res ---
    const size_t base = (size_t)blockIdx.x * 64 * DD;
#pragma unroll
    for (int i = 0; i < 8; ++i) {
        const int e = i * 512 + tid;
        const int p = e >> 6;
        const int d = e & 63;
        const int ix = fidx[p];
        res_out[base + e] = res_in[base + e] - cbk[(size_t)ix * DD + d];  // exact fp32 sub
    }
}

// ---- finalize: quantized = x - residual ----
__global__ __launch_bounds__(256) void rvq_final(const float* __restrict__ x,
                                                 const float* __restrict__ res,
                                                 float* __restrict__ q) {
#pragma clang fp contract(off)
    int i = blockIdx.x * 256 + threadIdx.x;
    q[i] = x[i] - res[i];
}

extern "C" void kernel_launch(void* const* d_in, const int* in_sizes, int n_in,
                              void* d_out, int out_size, void* d_ws, size_t ws_size,
                              hipStream_t stream) {
    const float* x  = (const float*)d_in[0];
    const float* cb = (const float*)d_in[1];

    float* out = (float*)d_out;
    float* quant = out;                 // QSIZE floats
    float* idx_out = out + QSIZE;       // K*NPTS floats (indices as float)

    float* c2   = (float*)d_ws;                       // K*M floats (64 KB)
    float* res1 = c2 + (size_t)KK * MM;               // NPTS*D floats (8 MB), 16B-aligned
    float* R[2] = { quant, res1 };                    // ping-pong residual (R0 in d_out)

    rvq_prep<<<(KK * MM) / 256, 256, 0, stream>>>(cb, c2);

    for (int k = 0; k < KK; ++k) {
        const float* rin = (k == 0) ? x : R[(k - 1) & 1];
        float* rout = R[k & 1];
        rvq_step<<<NPTS / 64, 512, 0, stream>>>(
            rin, rout,
            cb + (size_t)k * MM * DD,
            c2 + (size_t)k * MM,
            idx_out + (size_t)k * NPTS);
    }

    rvq_final<<<QSIZE / 256, 256, 0, stream>>>(x, R[(KK - 1) & 1], quant);
}

// Round 5
// 1327.223 us; speedup vs baseline: 1.2928x; 1.2928x over previous
//
#include <hip/hip_runtime.h>

// Residual VQ, bit-exact replication of the numpy reference's fp32 rounding.
// B=16 S=2048 D=64 K=8 M=2048.
//
// Numerics contract (verified bit-exact R1-R4, absmax 0.0):
//  - r2/c2: numpy pairwise_sum 8-accumulator order, no FMA contraction
//  - cross: numpy einsum baseline-SSE order: 4 chains (d mod 4), per 16-block
//           groups at offsets {12,8,4,0}+j, blocks ascending, hsum (L0+L1)+(L2+L3)
//  - t = fl(r2 - 2*cross) via fma(-2,cross,r2); d2 = fl(t + c2)
//  - argmin: first occurrence (strict <; cross-chunk combine ascending-m)
//  - chain init-by-first-product == 0+t except ±0 cases, which cannot alter d2
//    (c2m > 0 absorbs signed zero) -> still bit-exact.
//
// R5: entire m-loop is ONE volatile asm block with hard physical registers.
// R2-R4 showed the allocator refuses to keep the 64-float residual in arch
// VGPRs (VGPR_Count stuck at 52; AGPR-shuffle / remat-reload per use). Here:
// rp pinned in v[16:79], codebook row s_load_dwordx16 -> s[32:95], scratch
// v[80:93]/s[28:31]. v_pk_* per-half IEEE-RN == scalar (R4 ran bit-exact).

#define BB 16
#define SS 2048
#define DD 64
#define KK 8
#define MM 2048
#define NPTS (BB * SS)      // 32768
#define QSIZE (NPTS * DD)   // 2097152
#define WPB 8               // waves per block
#define MCHUNK (MM / WPB)   // 256 m per wave

// ---- prep: c2[k][m] (numpy pairwise) ----
__global__ __launch_bounds__(256) void rvq_prep(const float* __restrict__ cb,
                                                float* __restrict__ c2) {
#pragma clang fp contract(off)
    int tid = blockIdx.x * 256 + threadIdx.x;  // 0 .. K*M-1
    const float* row = cb + (size_t)tid * DD;
    float r[8];
#pragma unroll
    for (int j = 0; j < 8; ++j) { float v = row[j]; r[j] = v * v; }
#pragma unroll
    for (int i = 8; i < DD; i += 8) {
#pragma unroll
        for (int j = 0; j < 8; ++j) { float v = row[i + j]; float t = v * v; r[j] += t; }
    }
    c2[tid] = ((r[0] + r[1]) + (r[2] + r[3])) + ((r[4] + r[5]) + (r[6] + r[7]));
}

// r2 chain block for k-th 8-float group (bases A=16+8k, etc.)
#define R2K(A, B, C, E) \
    "v_pk_mul_f32 v[92:93], v[" A "], v[" A "]\n\t" \
    "v_pk_add_f32 v[80:81], v[80:81], v[92:93]\n\t" \
    "v_pk_mul_f32 v[92:93], v[" B "], v[" B "]\n\t" \
    "v_pk_add_f32 v[82:83], v[82:83], v[92:93]\n\t" \
    "v_pk_mul_f32 v[92:93], v[" C "], v[" C "]\n\t" \
    "v_pk_add_f32 v[84:85], v[84:85], v[92:93]\n\t" \
    "v_pk_mul_f32 v[92:93], v[" E "], v[" E "]\n\t" \
    "v_pk_add_f32 v[86:87], v[86:87], v[92:93]\n\t"

// einsum group at offset d0: s-pairs (32+d0, 34+d0), v-pairs (16+d0, 18+d0)
#define GRP(SA, SB, VA, VB) \
    "v_pk_mul_f32 v[84:85], s[" SA "], v[" VA "]\n\t" \
    "v_pk_mul_f32 v[86:87], s[" SB "], v[" VB "]\n\t" \
    "v_pk_add_f32 v[80:81], v[80:81], v[84:85]\n\t" \
    "v_pk_add_f32 v[82:83], v[82:83], v[86:87]\n\t"

// ---- one RVQ step ----
// grid = NPTS/64 = 512 blocks x 512 threads (8 waves).
// lane = point within the block's 64-point group; wave = m-chunk.
__global__ __launch_bounds__(512, 4) void rvq_step(const float* __restrict__ res_in,
                                                   float* __restrict__ res_out,
                                                   const float* __restrict__ cbk,  // (M,D)
                                                   const float* __restrict__ c2k,  // (M,)
                                                   float* __restrict__ idx_out) {  // (NPTS,)
#pragma clang fp contract(off)
    const int tid = threadIdx.x;
    const int lane = tid & 63;
    const int wv = __builtin_amdgcn_readfirstlane(tid >> 6);  // wave-uniform
    const int point = blockIdx.x * 64 + lane;

    const int m0 = wv * MCHUNK;
    const float* cbw = cbk + (size_t)m0 * DD;   // this wave's chunk base
    const float* c2w = c2k + m0;
    const unsigned long long ra = (unsigned long long)(res_in + (size_t)point * DD);

    float best;
    int bidx;
    asm volatile(
        // ---- residual: 64 floats -> v[16:79] ----
        "global_load_dwordx4 v[16:19], %[ra], off\n\t"
        "global_load_dwordx4 v[20:23], %[ra], off offset:16\n\t"
        "global_load_dwordx4 v[24:27], %[ra], off offset:32\n\t"
        "global_load_dwordx4 v[28:31], %[ra], off offset:48\n\t"
        "global_load_dwordx4 v[32:35], %[ra], off offset:64\n\t"
        "global_load_dwordx4 v[36:39], %[ra], off offset:80\n\t"
        "global_load_dwordx4 v[40:43], %[ra], off offset:96\n\t"
        "global_load_dwordx4 v[44:47], %[ra], off offset:112\n\t"
        "global_load_dwordx4 v[48:51], %[ra], off offset:128\n\t"
        "global_load_dwordx4 v[52:55], %[ra], off offset:144\n\t"
        "global_load_dwordx4 v[56:59], %[ra], off offset:160\n\t"
        "global_load_dwordx4 v[60:63], %[ra], off offset:176\n\t"
        "global_load_dwordx4 v[64:67], %[ra], off offset:192\n\t"
        "global_load_dwordx4 v[68:71], %[ra], off offset:208\n\t"
        "global_load_dwordx4 v[72:75], %[ra], off offset:224\n\t"
        "global_load_dwordx4 v[76:79], %[ra], off offset:240\n\t"
        "s_waitcnt vmcnt(0)\n\t"
        // ---- r2, numpy pairwise 8-acc order; accs (r0,r1)..(r6,r7) in v[80:87] ----
        "v_pk_mul_f32 v[80:81], v[16:17], v[16:17]\n\t"
        "v_pk_mul_f32 v[82:83], v[18:19], v[18:19]\n\t"
        "v_pk_mul_f32 v[84:85], v[20:21], v[20:21]\n\t"
        "v_pk_mul_f32 v[86:87], v[22:23], v[22:23]\n\t"
        R2K("24:25", "26:27", "28:29", "30:31")
        R2K("32:33", "34:35", "36:37", "38:39")
        R2K("40:41", "42:43", "44:45", "46:47")
        R2K("48:49", "50:51", "52:53", "54:55")
        R2K("56:57", "58:59", "60:61", "62:63")
        R2K("64:65", "66:67", "68:69", "70:71")
        R2K("72:73", "74:75", "76:77", "78:79")
        "v_add_f32 v92, v80, v81\n\t"
        "v_add_f32 v93, v82, v83\n\t"
        "v_add_f32 v92, v92, v93\n\t"
        "v_add_f32 v93, v84, v85\n\t"
        "v_add_f32 v88, v86, v87\n\t"
        "v_add_f32 v93, v93, v88\n\t"
        "v_add_f32 v88, v92, v93\n\t"          // r2 -> v88
        // ---- init ----
        "v_mov_b32 v89, 0x7f800000\n\t"        // best = +inf
        "v_mov_b32 v90, 0\n\t"                 // bidx = 0
        "s_mov_b32 s29, 0\n\t"                 // byte offset in chunk
        "Lrvq_%=:\n\t"
        // ---- codebook row m -> s[32:95]; c2m -> s28; m -> v91 ----
        "s_load_dwordx16 s[32:47], %[cb], s29\n\t"
        "s_add_u32 s30, s29, 64\n\t"
        "s_load_dwordx16 s[48:63], %[cb], s30\n\t"
        "s_add_u32 s30, s29, 128\n\t"
        "s_load_dwordx16 s[64:79], %[cb], s30\n\t"
        "s_add_u32 s30, s29, 192\n\t"
        "s_load_dwordx16 s[80:95], %[cb], s30\n\t"
        "s_lshr_b32 s31, s29, 6\n\t"
        "s_load_dword s28, %[c2], s31\n\t"
        "s_lshr_b32 s30, s29, 8\n\t"
        "s_add_u32 s30, s30, %[m0]\n\t"
        "v_mov_b32 v91, s30\n\t"
        "s_waitcnt lgkmcnt(0)\n\t"
        // ---- einsum: blocks ascending, groups {12,8,4,0}+b; chains in v[80:83] ----
        // b=0: d0=12 (init), 8, 4, 0
        "v_pk_mul_f32 v[80:81], s[44:45], v[28:29]\n\t"
        "v_pk_mul_f32 v[82:83], s[46:47], v[30:31]\n\t"
        GRP("40:41", "42:43", "24:25", "26:27")
        GRP("36:37", "38:39", "20:21", "22:23")
        GRP("32:33", "34:35", "16:17", "18:19")
        // b=16: d0=28, 24, 20, 16
        GRP("60:61", "62:63", "44:45", "46:47")
        GRP("56:57", "58:59", "40:41", "42:43")
        GRP("52:53", "54:55", "36:37", "38:39")
        GRP("48:49", "50:51", "32:33", "34:35")
        // b=32: d0=44, 40, 36, 32
        GRP("76:77", "78:79", "60:61", "62:63")
        GRP("72:73", "74:75", "56:57", "58:59")
        GRP("68:69", "70:71", "52:53", "54:55")
        GRP("64:65", "66:67", "48:49", "50:51")
        // b=48: d0=60, 56, 52, 48
        GRP("92:93", "94:95", "76:77", "78:79")
        GRP("88:89", "90:91", "72:73", "74:75")
        GRP("84:85", "86:87", "68:69", "70:71")
        GRP("80:81", "82:83", "64:65", "66:67")
        // ---- hsum, d2, argmin ----
        "v_add_f32 v92, v80, v81\n\t"
        "v_add_f32 v93, v82, v83\n\t"
        "v_add_f32 v92, v92, v93\n\t"          // cross
        "v_fma_f32 v92, v92, -2.0, v88\n\t"    // tt = -2*cross + r2 (single rounding)
        "v_add_f32 v92, s28, v92\n\t"          // d2 = tt + c2m (commutative, exact)
        "v_cmp_lt_f32 vcc, v92, v89\n\t"
        "v_cndmask_b32 v89, v89, v92, vcc\n\t"
        "v_cndmask_b32 v90, v90, v91, vcc\n\t"
        "s_add_u32 s29, s29, 256\n\t"
        "s_cmp_lg_u32 s29, 0x10000\n\t"
        "s_cbranch_scc1 Lrvq_%=\n\t"
        "v_mov_b32 %[ob], v89\n\t"
        "v_mov_b32 %[oi], v90\n\t"
        : [ob] "=v"(best), [oi] "=v"(bidx)
        : [ra] "v"(ra), [cb] "s"(cbw), [c2] "s"(c2w), [m0] "s"(m0)
        : "vcc", "scc",
          "v16","v17","v18","v19","v20","v21","v22","v23","v24","v25","v26","v27",
          "v28","v29","v30","v31","v32","v33","v34","v35","v36","v37","v38","v39",
          "v40","v41","v42","v43","v44","v45","v46","v47","v48","v49","v50","v51",
          "v52","v53","v54","v55","v56","v57","v58","v59","v60","v61","v62","v63",
          "v64","v65","v66","v67","v68","v69","v70","v71","v72","v73","v74","v75",
          "v76","v77","v78","v79","v80","v81","v82","v83","v84","v85","v86","v87",
          "v88","v89","v90","v91","v92","v93",
          "s28","s29","s30","s31","s32","s33","s34","s35","s36","s37","s38","s39",
          "s40","s41","s42","s43","s44","s45","s46","s47","s48","s49","s50","s51",
          "s52","s53","s54","s55","s56","s57","s58","s59","s60","s61","s62","s63",
          "s64","s65","s66","s67","s68","s69","s70","s71","s72","s73","s74","s75",
          "s76","s77","s78","s79","s80","s81","s82","s83","s84","s85","s86","s87",
          "s88","s89","s90","s91","s92","s93","s94","s95");

    // --- combine across the 8 m-chunks (waves), first-occurrence semantics ---
    __shared__ float sb[WPB * 64];
    __shared__ int   si[WPB * 64];
    __shared__ int   fidx[64];
    sb[wv * 64 + lane] = best;
    si[wv * 64 + lane] = bidx;
    __syncthreads();
    if (tid < 64) {
        float b = sb[lane];
        int ix = si[lane];
#pragma unroll
        for (int w = 1; w < WPB; ++w) {
            float ob = sb[w * 64 + lane];
            int oi = si[w * 64 + lane];
            if (ob < b) { b = ob; ix = oi; }  // strict <: smaller-m chunk wins ties
        }
        fidx[lane] = ix;
        idx_out[point] = (float)ix;  // exact for ix < 2^24
    }
    __syncthreads();

    // --- residual update: 512 threads x 8 elems, coalesced on res ---
    const size_t base = (size_t)blockIdx.x * 64 * DD;
#pragma unroll
    for (int i = 0; i < 8; ++i) {
        const int e = i * 512 + tid;
        const int p = e >> 6;
        const int d = e & 63;
        const int ix = fidx[p];
        res_out[base + e] = res_in[base + e] - cbk[(size_t)ix * DD + d];  // exact fp32 sub
    }
}

// ---- finalize: quantized = x - residual ----
__global__ __launch_bounds__(256) void rvq_final(const float* __restrict__ x,
                                                 const float* __restrict__ res,
                                                 float* __restrict__ q) {
#pragma clang fp contract(off)
    int i = blockIdx.x * 256 + threadIdx.x;
    q[i] = x[i] - res[i];
}

extern "C" void kernel_launch(void* const* d_in, const int* in_sizes, int n_in,
                              void* d_out, int out_size, void* d_ws, size_t ws_size,
                              hipStream_t stream) {
    const float* x  = (const float*)d_in[0];
    const float* cb = (const float*)d_in[1];

    float* out = (float*)d_out;
    float* quant = out;                 // QSIZE floats
    float* idx_out = out + QSIZE;       // K*NPTS floats (indices as float)

    float* c2   = (float*)d_ws;                       // K*M floats (64 KB)
    float* res1 = c2 + (size_t)KK * MM;               // NPTS*D floats (8 MB), 16B-aligned
    float* R[2] = { quant, res1 };                    // ping-pong residual (R0 in d_out)

    rvq_prep<<<(KK * MM) / 256, 256, 0, stream>>>(cb, c2);

    for (int k = 0; k < KK; ++k) {
        const float* rin = (k == 0) ? x : R[(k - 1) & 1];
        float* rout = R[k & 1];
        rvq_step<<<NPTS / 64, 512, 0, stream>>>(
            rin, rout,
            cb + (size_t)k * MM * DD,
            c2 + (size_t)k * MM,
            idx_out + (size_t)k * NPTS);
    }

    rvq_final<<<QSIZE / 256, 256, 0, stream>>>(x, R[(KK - 1) & 1], quant);
}